// Round 14
// baseline (125.447 us; speedup 1.0000x reference)
//
#include <hip/hip_runtime.h>
#include <hip/hip_bf16.h>

#define IN_F 4096
#define LOCAL_F 128
#define KSZ 64
#define STRIDE_ 32
#define FOLDS 127
#define BATCH_ 4096
#define OUT_F (FOLDS * LOCAL_F)    // 16256
#define WN (FOLDS * LOCAL_F * KSZ) // 1040384

#define ROWS 16
#define LPAD 8                      // row stride 4104 shorts = 8208 B: 16B-aligned, 2-way max
#define LSTR (IN_F + LPAD)          // 4104

typedef __attribute__((ext_vector_type(8))) short bf16x8;
typedef __attribute__((ext_vector_type(8))) unsigned short u16x8;
typedef __attribute__((ext_vector_type(4))) float f32x4;

__device__ __forceinline__ unsigned short f2bf(float f) {
    unsigned u = __builtin_bit_cast(unsigned, f);
    u += 0x7fffu + ((u >> 16) & 1u);   // round-to-nearest-even
    return (unsigned short)(u >> 16);
}

// ---- prep: W fp32 -> bf16 (4 MB read / 2 MB write) ----
__global__ __launch_bounds__(256)
void wprep_kernel(const float* __restrict__ W, unsigned short* __restrict__ Wbf) {
    int i = (blockIdx.x * 256 + threadIdx.x) * 8;
    if (i >= WN) return;
    float4 a = *reinterpret_cast<const float4*>(W + i);
    float4 c = *reinterpret_cast<const float4*>(W + i + 4);
    u16x8 s;
    s[0] = f2bf(a.x); s[1] = f2bf(a.y); s[2] = f2bf(a.z); s[3] = f2bf(a.w);
    s[4] = f2bf(c.x); s[5] = f2bf(c.y); s[6] = f2bf(c.z); s[7] = f2bf(c.w);
    *reinterpret_cast<u16x8*>(Wbf + i) = s;
}

// ---- main: block = 16 rows x ALL 127 folds, 1024 threads, grid 256 = 1 block/CU.
// x staged as FULL ROWS (16 KB sequential per row, read once globally) -> HBM
// page-dense reads. 16 waves x 8 folds; spread NT stores (16-wave dense front).
__global__ __launch_bounds__(1024, 1)
void ll_main(const float* __restrict__ x,
             const unsigned short* __restrict__ Wbf,
             const float* __restrict__ b,
             float* __restrict__ out) {
    __shared__ unsigned short xs[ROWS][LSTR];   // 131.3 KB

    const int rg = blockIdx.x;            // 0..255
    const int row0 = rg * ROWS;
    const int t = threadIdx.x;            // 0..1023

    // ---- stage 16 rows x 4096 fp32 -> bf16 LDS; 8 iters x 8 floats/thread ----
    #pragma unroll
    for (int it = 0; it < 8; ++it) {
        const int idx = it * 8192 + t * 8;      // flat elem in 16x4096
        const int r = idx >> 12;                // /4096
        const int c = idx & 4095;
        const float* p = x + (size_t)(row0 + r) * IN_F + c;
        f32x4 a = *reinterpret_cast<const f32x4*>(p);
        f32x4 d = *reinterpret_cast<const f32x4*>(p + 4);
        u16x8 s;
        s[0] = f2bf(a[0]); s[1] = f2bf(a[1]); s[2] = f2bf(a[2]); s[3] = f2bf(a[3]);
        s[4] = f2bf(d[0]); s[5] = f2bf(d[1]); s[6] = f2bf(d[2]); s[7] = f2bf(d[3]);
        *reinterpret_cast<u16x8*>(&xs[r][c]) = s;   // b128, conflict-free
    }
    __syncthreads();

    const int w    = t >> 6;              // wave 0..15
    const int lane = t & 63;
    const int l16  = lane & 15;
    const int g    = lane >> 4;

    float*       orow = out + (size_t)(row0 + l16) * OUT_F + 4 * g;

    #pragma unroll
    for (int j = 0; j < 8; ++j) {
        const int f = w + 16 * j;         // wave-uniform; only w=15,j=7 -> 127 skipped
        if (f < FOLDS) {
            // ---- x fragments from LDS: row l16, cols f*32 + ks*32 + g*8 ----
            bf16x8 af0 = *reinterpret_cast<const bf16x8*>(&xs[l16][f * STRIDE_ + g * 8]);
            bf16x8 af1 = *reinterpret_cast<const bf16x8*>(&xs[l16][f * STRIDE_ + 32 + g * 8]);

            f32x4 acc[8];
            #pragma unroll
            for (int nt = 0; nt < 8; ++nt) acc[nt] = (f32x4){0.f, 0.f, 0.f, 0.f};

            // ---- W fragments (L2-resident bf16) + MFMA, ks-staged ----
            const unsigned short* Wf = Wbf + (size_t)f * (LOCAL_F * KSZ) + l16 * KSZ + g * 8;
            {
                bf16x8 wf[8];
                #pragma unroll
                for (int nt = 0; nt < 8; ++nt)
                    wf[nt] = *reinterpret_cast<const bf16x8*>(Wf + nt * 16 * KSZ);
                #pragma unroll
                for (int nt = 0; nt < 8; ++nt)
                    acc[nt] = __builtin_amdgcn_mfma_f32_16x16x32_bf16(wf[nt], af0, acc[nt], 0, 0, 0);
            }
            {
                bf16x8 wf[8];
                #pragma unroll
                for (int nt = 0; nt < 8; ++nt)
                    wf[nt] = *reinterpret_cast<const bf16x8*>(Wf + nt * 16 * KSZ + 32);
                #pragma unroll
                for (int nt = 0; nt < 8; ++nt)
                    acc[nt] = __builtin_amdgcn_mfma_f32_16x16x32_bf16(wf[nt], af1, acc[nt], 0, 0, 0);
            }

            // ---- bias + spread NT stores; lane owns batch row l16, feat f*128+nt*16+4g ----
            #pragma unroll
            for (int nt = 0; nt < 8; ++nt) {
                f32x4 bv = *reinterpret_cast<const f32x4*>(b + (size_t)f * LOCAL_F + nt * 16 + 4 * g);
                f32x4 v = acc[nt] + bv;
                __builtin_nontemporal_store(v,
                    reinterpret_cast<f32x4*>(orow + (size_t)f * LOCAL_F + nt * 16));
            }
        }
    }
}

extern "C" void kernel_launch(void* const* d_in, const int* in_sizes, int n_in,
                              void* d_out, int out_size, void* d_ws, size_t ws_size,
                              hipStream_t stream) {
    const float* x = (const float*)d_in[0];
    const float* W = (const float*)d_in[1];
    const float* b = (const float*)d_in[2];
    float* out = (float*)d_out;
    unsigned short* Wbf = (unsigned short*)d_ws;

    wprep_kernel<<<(WN / 8 + 255) / 256, 256, 0, stream>>>(W, Wbf);
    ll_main<<<dim3(256), 1024, 0, stream>>>(x, Wbf, b, out);
}

// Round 16
// 102.998 us; speedup vs baseline: 1.2180x; 1.2180x over previous
//
#include <hip/hip_runtime.h>
#include <hip/hip_bf16.h>

#define IN_F 4096
#define LOCAL_F 128
#define KSZ 64
#define STRIDE_ 32
#define FOLDS 127
#define BATCH_ 4096
#define OUT_F (FOLDS * LOCAL_F)    // 16256
#define WN (FOLDS * LOCAL_F * KSZ) // 1040384

#define ROWS 16
#define FPB 8                       // folds per block
#define LDSW (FPB * LOCAL_F + 4)    // 1028 floats: +4 pad -> conflict-free b128

typedef __attribute__((ext_vector_type(8))) short bf16x8;
typedef __attribute__((ext_vector_type(8))) unsigned short u16x8;
typedef __attribute__((ext_vector_type(4))) float f32x4;

__device__ __forceinline__ unsigned short f2bf(float f) {
    unsigned u = __builtin_bit_cast(unsigned, f);
    u += 0x7fffu + ((u >> 16) & 1u);   // round-to-nearest-even
    return (unsigned short)(u >> 16);
}

// ---- prep: W fp32 -> bf16 (4 MB read / 2 MB write) ----
__global__ __launch_bounds__(256)
void wprep_kernel(const float* __restrict__ W, unsigned short* __restrict__ Wbf) {
    int i = (blockIdx.x * 256 + threadIdx.x) * 8;
    if (i >= WN) return;
    float4 a = *reinterpret_cast<const float4*>(W + i);
    float4 c = *reinterpret_cast<const float4*>(W + i + 4);
    u16x8 s;
    s[0] = f2bf(a.x); s[1] = f2bf(a.y); s[2] = f2bf(a.z); s[3] = f2bf(a.w);
    s[4] = f2bf(c.x); s[5] = f2bf(c.y); s[6] = f2bf(c.z); s[7] = f2bf(c.w);
    *reinterpret_cast<u16x8*>(Wbf + i) = s;
}

// ---- main: block = 16 rows x 8 folds; MFMA -> LDS transpose -> DENSE NONTEMPORAL bursts ----
__global__ __launch_bounds__(256, 2)
void ll_main(const float* __restrict__ x,
             const unsigned short* __restrict__ Wbf,
             const float* __restrict__ b,
             float* __restrict__ out) {
    __shared__ float os[ROWS][LDSW];

    const int fqb = blockIdx.x;           // 0..15  (folds fqb*8 .. fqb*8+7)
    const int rg  = blockIdx.y;           // 0..255 (16-row batch band)
    const int row0 = rg * ROWS;

    const int wave = threadIdx.x >> 6;
    const int lane = threadIdx.x & 63;
    const int l16 = lane & 15;
    const int g   = lane >> 4;

    #pragma unroll
    for (int p = 0; p < 2; ++p) {
        const int fl = wave * 2 + p;      // fold-local 0..7
        const int f  = fqb * FPB + fl;
        if (f < FOLDS) {
            // ---- x fragments: lane holds x[row0+l16][f*32 + ks*32 + g*8 + 0..7] ----
            const float* xp = x + (size_t)(row0 + l16) * IN_F + f * STRIDE_ + g * 8;
            f32x4 xa0 = *reinterpret_cast<const f32x4*>(xp);
            f32x4 xa1 = *reinterpret_cast<const f32x4*>(xp + 4);
            f32x4 xb0 = *reinterpret_cast<const f32x4*>(xp + 32);
            f32x4 xb1 = *reinterpret_cast<const f32x4*>(xp + 36);

            // ---- W fragments: lane holds W[f][nt*16 + l16][ks*32 + g*8 + 0..7] ----
            const unsigned short* Wf = Wbf + (size_t)f * (LOCAL_F * KSZ) + l16 * KSZ + g * 8;
            bf16x8 wf[2][8];
            #pragma unroll
            for (int nt = 0; nt < 8; ++nt) {
                wf[0][nt] = *reinterpret_cast<const bf16x8*>(Wf + nt * 16 * KSZ);
                wf[1][nt] = *reinterpret_cast<const bf16x8*>(Wf + nt * 16 * KSZ + 32);
            }

            bf16x8 af0, af1;
            af0[0] = (short)f2bf(xa0[0]); af0[1] = (short)f2bf(xa0[1]);
            af0[2] = (short)f2bf(xa0[2]); af0[3] = (short)f2bf(xa0[3]);
            af0[4] = (short)f2bf(xa1[0]); af0[5] = (short)f2bf(xa1[1]);
            af0[6] = (short)f2bf(xa1[2]); af0[7] = (short)f2bf(xa1[3]);
            af1[0] = (short)f2bf(xb0[0]); af1[1] = (short)f2bf(xb0[1]);
            af1[2] = (short)f2bf(xb0[2]); af1[3] = (short)f2bf(xb0[3]);
            af1[4] = (short)f2bf(xb1[0]); af1[5] = (short)f2bf(xb1[1]);
            af1[6] = (short)f2bf(xb1[2]); af1[7] = (short)f2bf(xb1[3]);

            // ---- MFMA: D = W x X^T ; lane holds D[feat = nt*16 + 4g + i][batch = l16]
            f32x4 acc[8];
            #pragma unroll
            for (int nt = 0; nt < 8; ++nt) acc[nt] = (f32x4){0.f, 0.f, 0.f, 0.f};
            #pragma unroll
            for (int nt = 0; nt < 8; ++nt)
                acc[nt] = __builtin_amdgcn_mfma_f32_16x16x32_bf16(wf[0][nt], af0, acc[nt], 0, 0, 0);
            #pragma unroll
            for (int nt = 0; nt < 8; ++nt)
                acc[nt] = __builtin_amdgcn_mfma_f32_16x16x32_bf16(wf[1][nt], af1, acc[nt], 0, 0, 0);

            // ---- bias + stage to LDS: os[row=l16][fl*128 + nt*16 + 4g + 0..3] ----
            #pragma unroll
            for (int nt = 0; nt < 8; ++nt) {
                f32x4 bv = *reinterpret_cast<const f32x4*>(b + (size_t)f * LOCAL_F + nt * 16 + 4 * g);
                f32x4 v = acc[nt] + bv;
                *reinterpret_cast<f32x4*>(&os[l16][fl * LOCAL_F + nt * 16 + 4 * g]) = v;
            }
        }
    }
    __syncthreads();

    // ---- dense epilogue: per row, 256 threads write one 4-KB contiguous NT burst ----
    const int t = threadIdx.x;
    const int colbase = fqb * (FPB * LOCAL_F);   // fqb*1024
    const int col = colbase + 4 * t;
    #pragma unroll
    for (int r = 0; r < ROWS; ++r) {
        if (col < OUT_F) {
            f32x4 v = *reinterpret_cast<const f32x4*>(&os[r][4 * t]);
            __builtin_nontemporal_store(v,
                reinterpret_cast<f32x4*>(out + (size_t)(row0 + r) * OUT_F + col));
        }
    }
}

extern "C" void kernel_launch(void* const* d_in, const int* in_sizes, int n_in,
                              void* d_out, int out_size, void* d_ws, size_t ws_size,
                              hipStream_t stream) {
    const float* x = (const float*)d_in[0];
    const float* W = (const float*)d_in[1];
    const float* b = (const float*)d_in[2];
    float* out = (float*)d_out;
    unsigned short* Wbf = (unsigned short*)d_ws;

    wprep_kernel<<<(WN / 8 + 255) / 256, 256, 0, stream>>>(W, Wbf);
    dim3 grid(16, BATCH_ / ROWS);   // fqb fastest -> dense global write front
    ll_main<<<grid, 256, 0, stream>>>(x, Wbf, b, out);
}